// Round 16
// baseline (195.642 us; speedup 1.0000x reference)
//
#include <hip/hip_runtime.h>

typedef unsigned short ushort;
typedef __attribute__((ext_vector_type(4))) float floatx4;
typedef __bf16 bf16x8 __attribute__((ext_vector_type(8)));
typedef __bf16 bf16x4 __attribute__((ext_vector_type(4)));
typedef float f32x4 __attribute__((ext_vector_type(4)));

constexpr int NB = 4;     // batch
constexpr int NL = 1024;  // seq len
constexpr int ND = 1024;  // d_model
constexpr int NH = 16;    // heads
constexpr int NDK = 64;   // d_k = d_v

// Q is pre-scaled by log2(e)/32 so attn computes exp2(score) directly.
#define QSCALE 0.045084230079650879f

union B4 { bf16x4 v; unsigned long long ll; };

__device__ __forceinline__ void st_bf(ushort* dst, float f){
  union { __bf16 h; ushort u; } z; z.h = (__bf16)f; *dst = z.u;
}

#define MFMA(a,b,c) __builtin_amdgcn_mfma_f32_16x16x32_bf16((a),(b),(c),0,0,0)

// ---------------------------------------------------------------------------
// K0: prep = weight transposes ONLY (768 blocks).  Everything not needed by
// k_projm itself (maskpack, proj_w cast, BN zeroing) is hidden inside
// k_projm's z==3 slice, overlapping with its GEMM blocks.
// ---------------------------------------------------------------------------
__global__ __launch_bounds__(256) void k_prep(const float* __restrict__ w0,
                                              const float* __restrict__ w1,
                                              const float* __restrict__ w2,
                                              ushort* __restrict__ t0,
                                              ushort* __restrict__ t1,
                                              ushort* __restrict__ t2){
  __shared__ ushort T[64][65];
  const int r = blockIdx.x;
  const int tid = threadIdx.x;
  const int z = r >> 8;
  const int h = (r >> 4) & 15, k0 = (r & 15) * 64;
  const float* src = (z == 0) ? w0 : (z == 1) ? w1 : w2;
  ushort* dst = (z == 0) ? t0 : (z == 1) ? t1 : t2;
  const int qd = tid >> 6, lo = tid & 63;
  #pragma unroll
  for (int i = 0; i < 16; i++){
    int kl = qd + i * 4;
    float f = src[((size_t)h * 1024 + k0 + kl) * 64 + lo];
    union { __bf16 h2; ushort u; } zz; zz.h2 = (__bf16)f;
    T[kl][lo] = zz.u;
  }
  __syncthreads();
  #pragma unroll
  for (int i = 0; i < 16; i++){
    int dk = qd + i * 4;
    dst[((size_t)h * 64 + dk) * 1024 + k0 + lo] = T[lo][dk];
  }
}

// ---------------------------------------------------------------------------
// K1: merged projections (z = 0:Q 1:K 2:V).  fp32 inputs, cast inline during
// A-staging.  z==0 epilogue pre-scaled by QSCALE; z==2 writes transposed
// VT(hb,64,1024).  z==3: 256 streaming blocks doing maskpack + proj_w cast +
// BN-partial zeroing, overlapped with the GEMM slices (their outputs are only
// consumed by LATER dispatches).  XOR bank swizzle; XCD tile remap.
// ---------------------------------------------------------------------------
__global__ __launch_bounds__(256) void k_projm(const float* __restrict__ qf,
                                               const float* __restrict__ kf,
                                               const float* __restrict__ vf,
                                               const ushort* __restrict__ wqT,
                                               const ushort* __restrict__ wkT,
                                               const ushort* __restrict__ wvT,
                                               ushort* __restrict__ qh,
                                               ushort* __restrict__ kh,
                                               ushort* __restrict__ vt,
                                               const float* __restrict__ pw,
                                               ushort* __restrict__ pwb,
                                               const int* __restrict__ M,
                                               unsigned long long* __restrict__ MB,
                                               float* __restrict__ part){
  const int z = blockIdx.z;
  const int tid = threadIdx.x;
  const int d = blockIdx.y * 8 + blockIdx.x;

  if (z == 3){
    const int idx = d;                  // 0..255
    // ---- mask pack: 16384 elems per block, 64 ballot reps ----
    #pragma unroll 4
    for (int rep = 0; rep < 64; rep++){
      const int gid = idx * 16384 + rep * 256 + tid;
      const int widx = gid >> 6;
      int m = M[(size_t)widx * 64 + (gid & 63)];
      unsigned long long bal = __ballot(m != 0);
      if ((gid & 63) == 0) MB[widx] = bal;
    }
    // ---- proj_w cast: 2 chunks of 8 floats per thread ----
    #pragma unroll
    for (int ch = 0; ch < 2; ch++){
      const size_t base = ((size_t)(ch * 256 + idx) * 256 + tid) * 8;
      floatx4 v0 = *(const floatx4*)(pw + base);
      floatx4 v1 = *(const floatx4*)(pw + base + 4);
      bf16x8 o;
      #pragma unroll
      for (int j = 0; j < 4; j++){ o[j] = (__bf16)v0[j]; o[4 + j] = (__bf16)v1[j]; }
      *(bf16x8*)(pwb + base) = o;
    }
    // ---- zero BN partials ----
    if (idx == 0){
      *(floatx4*)(part + tid * 8) = f32x4{0.f, 0.f, 0.f, 0.f};
      *(floatx4*)(part + tid * 8 + 4) = f32x4{0.f, 0.f, 0.f, 0.f};
    }
    return;
  }

  __shared__ bf16x8 Ach[8 * 128];
  __shared__ bf16x8 Bch[8 * 128];
  const float* Xf = (z == 0) ? qf : (z == 1) ? kf : vf;
  const ushort* WT = (z == 0) ? wqT : (z == 1) ? wkT : wvT;
  const int lane = tid & 63, wid = tid >> 6;
  const int g = lane >> 4, c = lane & 15;
  const int tile = (d & 7) * 32 + (d >> 3);
  const int row0 = (tile >> 3) * 128, col0 = (tile & 7) * 128;
  const int wm = (wid >> 1) * 64, wn = (wid & 1) * 64;

  f32x4 zero = {0.f, 0.f, 0.f, 0.f};
  f32x4 acc[4][4];
  #pragma unroll
  for (int i = 0; i < 4; i++)
    #pragma unroll
    for (int j = 0; j < 4; j++) acc[i][j] = zero;

  for (int k0 = 0; k0 < ND; k0 += 64){
    #pragma unroll
    for (int i = 0; i < 4; i++){
      int e = tid + i * 256;
      int kc = e & 7, m = e >> 3;
      const float* src = Xf + (size_t)(row0 + m) * ND + k0 + kc * 8;
      floatx4 v0 = *(const floatx4*)src;
      floatx4 v1 = *(const floatx4*)(src + 4);
      bf16x8 pb;
      #pragma unroll
      for (int j = 0; j < 4; j++){ pb[j] = (__bf16)v0[j]; pb[4 + j] = (__bf16)v1[j]; }
      Ach[kc * 128 + (m ^ kc)] = pb;
    }
    #pragma unroll
    for (int i = 0; i < 4; i++){
      int e = tid + i * 256;
      int kc = e & 7, n = e >> 3;
      int hh = (col0 + n) >> 6, dk = (col0 + n) & 63;
      Bch[kc * 128 + (n ^ kc)] = *(const bf16x8*)(WT + ((size_t)(hh << 6) + dk) * 1024 + k0 + kc * 8);
    }
    __syncthreads();
    bf16x8 bfr[4][2];
    #pragma unroll
    for (int ni = 0; ni < 4; ni++){
      int n = wn + ni * 16 + c;
      bfr[ni][0] = Bch[g * 128 + (n ^ g)];
      bfr[ni][1] = Bch[(4 + g) * 128 + (n ^ (4 + g))];
    }
    #pragma unroll
    for (int mi = 0; mi < 4; mi++){
      int m = wm + mi * 16 + c;
      bf16x8 a0 = Ach[g * 128 + (m ^ g)];
      bf16x8 a1 = Ach[(4 + g) * 128 + (m ^ (4 + g))];
      #pragma unroll
      for (int ni = 0; ni < 4; ni++){
        acc[mi][ni] = MFMA(a0, bfr[ni][0], acc[mi][ni]);
        acc[mi][ni] = MFMA(a1, bfr[ni][1], acc[mi][ni]);
      }
    }
    __syncthreads();
  }
  if (z == 2){
    #pragma unroll
    for (int mi = 0; mi < 4; mi++){
      #pragma unroll
      for (int ni = 0; ni < 4; ni++){
        int n = col0 + wn + ni * 16 + c;
        int hh = n >> 6, dk = n & 63;
        int m0 = row0 + wm + mi * 16 + g * 4;
        int bb = m0 >> 10, l = m0 & 1023;
        B4 o;
        #pragma unroll
        for (int r = 0; r < 4; r++) o.v[r] = (__bf16)acc[mi][ni][r];
        *(unsigned long long*)(vt + (((size_t)hh * NB + bb) * 64 + dk) * 1024 + l) = o.ll;
      }
    }
  } else {
    ushort* OUT = (z == 0) ? qh : kh;
    const float sc = (z == 0) ? QSCALE : 1.0f;
    #pragma unroll
    for (int mi = 0; mi < 4; mi++){
      #pragma unroll
      for (int ni = 0; ni < 4; ni++){
        #pragma unroll
        for (int r = 0; r < 4; r++){
          int m = row0 + wm + mi * 16 + g * 4 + r;
          int n = col0 + wn + ni * 16 + c;
          int bb = m >> 10, ls = m & 1023;
          int hh = n >> 6, dk = n & 63;
          st_bf(OUT + (((size_t)hh * NB + bb) * NL + ls) * NDK + dk, acc[mi][ni][r] * sc);
        }
      }
    }
  }
}

// ---------------------------------------------------------------------------
// K2: fused attention (r11 structure: 256 thr, two barriers per tile, T14
// register prefetch).  Pass 2 seeds the MFMA C-operand with -log2(denom) so
// p = exp2(a) directly (no per-element normalize mul).
// ---------------------------------------------------------------------------
__global__ __launch_bounds__(256, 4) void k_attn(const ushort* __restrict__ QH,
                                                 const ushort* __restrict__ KH,
                                                 const ushort* __restrict__ VT,
                                                 const unsigned* __restrict__ MB,
                                                 float* __restrict__ ATT,
                                                 ushort* __restrict__ CTX){
  __shared__ bf16x8 Kch[512];        // [sr][kc^(sr&7)]
  __shared__ bf16x8 Vch[512];        // [kc][dv^kc]
  __shared__ ushort Ps[4][16][72];
  __shared__ unsigned Ms[64 * 33];
  const int tid = threadIdx.x;
  const int lane = tid & 63, wid = tid >> 6;
  const int g = lane >> 4, c = lane & 15;
  const int d = blockIdx.y * 16 + blockIdx.x;
  const int tile = (d & 7) * 128 + (d >> 3);
  const int hb = tile >> 4;
  const int q0 = (tile & 15) * 64;
  const int h = hb >> 2, b = hb & 3;

  const int q = q0 + wid * 16 + c;
  const size_t qkbase = (size_t)hb * NL;

  bf16x8 qf0 = *(const bf16x8*)(QH + (qkbase + q) * NDK + g * 8);
  bf16x8 qf1 = *(const bf16x8*)(QH + (qkbase + q) * NDK + 32 + g * 8);

  {
    const unsigned* mbase = MB + ((size_t)(b << 10) + q0) * 32;
    #pragma unroll
    for (int i = 0; i < 8; i++){
      int idx = tid + i * 256;
      int ql2 = idx >> 5, word = idx & 31;
      Ms[ql2 * 33 + word] = mbase[ql2 * 32 + word];
    }
  }
  const int ql = wid * 16 + c;
  const int mg = g * 4;

  // staging indices (constant per thread)
  const int i0 = tid * 2, i1 = tid * 2 + 1;
  const int sr0 = i0 >> 3, kc0 = i0 & 7;
  const int sr1 = i1 >> 3, kc1 = i1 & 7;
  const int vdv0 = tid >> 3, vkc0 = tid & 7;            // idx = tid
  const int vdv1 = (tid + 256) >> 3, vkc1 = tid & 7;    // idx = tid + 256

  // ---- pass 1: denominators ----
  float rs = 0.f;
  bf16x8 kr0 = *(const bf16x8*)(KH + (qkbase + 0) * NDK + i0 * 8);
  bf16x8 kr1 = *(const bf16x8*)(KH + (qkbase + 0) * NDK + i1 * 8);
  for (int t = 0; t < 16; ++t){
    __syncthreads();
    Kch[sr0 * 8 + (kc0 ^ (sr0 & 7))] = kr0;
    Kch[sr1 * 8 + (kc1 ^ (sr1 & 7))] = kr1;
    __syncthreads();
    if (t < 15){
      const ushort* knext = KH + (qkbase + (t + 1) * 64) * NDK;
      kr0 = *(const bf16x8*)(knext + i0 * 8);
      kr1 = *(const bf16x8*)(knext + i1 * 8);
    }
    #pragma unroll
    for (int sub2 = 0; sub2 < 4; ++sub2){
      int s = sub2 * 16 + c;
      bf16x8 kf0 = Kch[s * 8 + (g ^ (s & 7))];
      bf16x8 kf1 = Kch[s * 8 + ((4 + g) ^ (s & 7))];
      f32x4 a = {0.f, 0.f, 0.f, 0.f};
      a = MFMA(kf0, qf0, a);
      a = MFMA(kf1, qf1, a);
      unsigned w = Ms[ql * 33 + t * 2 + (sub2 >> 1)];
      unsigned bits4 = (w >> (((sub2 & 1) << 4) + mg)) & 0xFu;
      #pragma unroll
      for (int r = 0; r < 4; r++)
        rs += ((bits4 >> r) & 1u) ? 0.f : __builtin_amdgcn_exp2f(a[r]);
    }
  }
  rs += __shfl_xor(rs, 16);
  rs += __shfl_xor(rs, 32);
  const float lsh = -__log2f(rs);

  // ---- pass 2: attns write + PV ----
  f32x4 acc[4];
  #pragma unroll
  for (int i = 0; i < 4; i++) acc[i] = f32x4{0.f, 0.f, 0.f, 0.f};
  const f32x4 cin = {lsh, lsh, lsh, lsh};

  kr0 = *(const bf16x8*)(KH + (qkbase + 0) * NDK + i0 * 8);
  kr1 = *(const bf16x8*)(KH + (qkbase + 0) * NDK + i1 * 8);
  bf16x8 vr0 = *(const bf16x8*)(VT + ((size_t)hb * 64 + vdv0) * 1024 + vkc0 * 8);
  bf16x8 vr1 = *(const bf16x8*)(VT + ((size_t)hb * 64 + vdv1) * 1024 + vkc1 * 8);

  for (int t = 0; t < 16; ++t){
    __syncthreads();
    Kch[sr0 * 8 + (kc0 ^ (sr0 & 7))] = kr0;
    Kch[sr1 * 8 + (kc1 ^ (sr1 & 7))] = kr1;
    Vch[vkc0 * 64 + (vdv0 ^ vkc0)] = vr0;
    Vch[vkc1 * 64 + (vdv1 ^ vkc1)] = vr1;
    __syncthreads();
    if (t < 15){
      const ushort* knext = KH + (qkbase + (t + 1) * 64) * NDK;
      kr0 = *(const bf16x8*)(knext + i0 * 8);
      kr1 = *(const bf16x8*)(knext + i1 * 8);
      const ushort* vnext = VT + (size_t)hb * 64 * 1024 + (t + 1) * 64;
      vr0 = *(const bf16x8*)(vnext + (size_t)vdv0 * 1024 + vkc0 * 8);
      vr1 = *(const bf16x8*)(vnext + (size_t)vdv1 * 1024 + vkc1 * 8);
    }
    #pragma unroll
    for (int sub2 = 0; sub2 < 4; ++sub2){
      int s = sub2 * 16 + c;
      bf16x8 kf0 = Kch[s * 8 + (g ^ (s & 7))];
      bf16x8 kf1 = Kch[s * 8 + ((4 + g) ^ (s & 7))];
      f32x4 a = cin;
      a = MFMA(kf0, qf0, a);
      a = MFMA(kf1, qf1, a);
      unsigned w = Ms[ql * 33 + t * 2 + (sub2 >> 1)];
      unsigned bits4 = (w >> (((sub2 & 1) << 4) + mg)) & 0xFu;
      floatx4 pn;
      B4 pw;
      #pragma unroll
      for (int r = 0; r < 4; r++){
        float p = ((bits4 >> r) & 1u) ? 0.f : __builtin_amdgcn_exp2f(a[r]);
        pn[r] = p;
        pw.v[r] = (__bf16)p;
      }
      *(floatx4*)(ATT + ((size_t)hb * NL + q) * NL + (t * 4 + sub2) * 16 + g * 4) = pn;
      *(unsigned long long*)&Ps[wid][c][sub2 * 16 + g * 4] = pw.ll;
    }
    #pragma unroll
    for (int ss = 0; ss < 2; ++ss){
      bf16x8 afr = *(bf16x8*)&Ps[wid][c][ss * 32 + g * 8];
      #pragma unroll
      for (int ni = 0; ni < 4; ni++){
        int kcr = ss * 4 + g;
        bf16x8 vfr = Vch[kcr * 64 + ((ni * 16 + c) ^ kcr)];
        acc[ni] = MFMA(afr, vfr, acc[ni]);
      }
    }
  }

  #pragma unroll
  for (int ni = 0; ni < 4; ni++)
    #pragma unroll
    for (int r = 0; r < 4; r++){
      int qq = q0 + wid * 16 + g * 4 + r;
      int dv = ni * 16 + c;
      st_bf(CTX + ((size_t)b * NL + qq) * ND + h * NDK + dv, acc[ni][r]);
    }
}

// ---------------------------------------------------------------------------
// K4: output projection + bias + residual + fused BN partial sums (atomics)
// ---------------------------------------------------------------------------
__global__ __launch_bounds__(256) void k_projo(const ushort* __restrict__ CTX,
                                               const ushort* __restrict__ PWb,
                                               const float* __restrict__ PB,
                                               const float* __restrict__ RES,
                                               float* __restrict__ X,
                                               float* __restrict__ part){
  __shared__ bf16x8 Ach[8 * 128];
  __shared__ bf16x8 Bch[8 * 128];
  const int tid = threadIdx.x;
  const int lane = tid & 63, wid = tid >> 6;
  const int g = lane >> 4, c = lane & 15;
  const int d = blockIdx.y * 8 + blockIdx.x;
  const int tile = (d & 7) * 32 + (d >> 3);
  const int row0 = (tile >> 3) * 128, col0 = (tile & 7) * 128;
  const int wm = (wid >> 1) * 64, wn = (wid & 1) * 64;

  f32x4 zero = {0.f, 0.f, 0.f, 0.f};
  f32x4 acc[4][4];
  #pragma unroll
  for (int i = 0; i < 4; i++)
    #pragma unroll
    for (int j = 0; j < 4; j++) acc[i][j] = zero;

  for (int k0 = 0; k0 < ND; k0 += 64){
    #pragma unroll
    for (int i = 0; i < 4; i++){
      int e = tid + i * 256;
      int kc = e & 7, m = e >> 3;
      Ach[kc * 128 + (m ^ kc)] = *(const bf16x8*)(CTX + (size_t)(row0 + m) * ND + k0 + kc * 8);
    }
    #pragma unroll
    for (int i = 0; i < 4; i++){
      int e = tid + i * 256;
      int kc = e & 7, n = e >> 3;
      Bch[kc * 128 + (n ^ kc)] = *(const bf16x8*)(PWb + (size_t)(col0 + n) * 1024 + k0 + kc * 8);
    }
    __syncthreads();
    bf16x8 bfr[4][2];
    #pragma unroll
    for (int ni = 0; ni < 4; ni++){
      int n = wn + ni * 16 + c;
      bfr[ni][0] = Bch[g * 128 + (n ^ g)];
      bfr[ni][1] = Bch[(4 + g) * 128 + (n ^ (4 + g))];
    }
    #pragma unroll
    for (int mi = 0; mi < 4; mi++){
      int m = wm + mi * 16 + c;
      bf16x8 a0 = Ach[g * 128 + (m ^ g)];
      bf16x8 a1 = Ach[(4 + g) * 128 + (m ^ (4 + g))];
      #pragma unroll
      for (int ni = 0; ni < 4; ni++){
        acc[mi][ni] = MFMA(a0, bfr[ni][0], acc[mi][ni]);
        acc[mi][ni] = MFMA(a1, bfr[ni][1], acc[mi][ni]);
      }
    }
    __syncthreads();
  }
  float s_[4] = {0.f, 0.f, 0.f, 0.f}, s2_[4] = {0.f, 0.f, 0.f, 0.f};
  #pragma unroll
  for (int mi = 0; mi < 4; mi++)
    #pragma unroll
    for (int ni = 0; ni < 4; ni++)
      #pragma unroll
      for (int r = 0; r < 4; r++){
        int m = row0 + wm + mi * 16 + g * 4 + r;
        int n = col0 + wn + ni * 16 + c;
        float val = acc[mi][ni][r] + PB[n] + RES[(size_t)m * ND + n];
        X[(size_t)m * ND + n] = val;
        s_[ni] += val; s2_[ni] += val * val;
      }
  #pragma unroll
  for (int ni = 0; ni < 4; ni++){
    float a = s_[ni], b2 = s2_[ni];
    a += __shfl_xor(a, 16); b2 += __shfl_xor(b2, 16);
    a += __shfl_xor(a, 32); b2 += __shfl_xor(b2, 32);
    if (g == 0){
      int n = col0 + wn + ni * 16 + c;
      atomicAdd(&part[n], a);
      atomicAdd(&part[1024 + n], b2);
    }
  }
}

// ---------------------------------------------------------------------------
// K5: BN finalize + apply in place (mean/rstd re-derived from the L2-hot
// 8 KB part array; plain stores — nontemporal regressed in r9/r10)
// ---------------------------------------------------------------------------
__global__ __launch_bounds__(256) void k_bnapply(float* __restrict__ X,
                                                 const float* __restrict__ part,
                                                 const float* __restrict__ G,
                                                 const float* __restrict__ Bt){
  const int idx = blockIdx.x * 256 + threadIdx.x;
  const size_t base = (size_t)idx * 8;
  const int d0 = (int)(base & (ND - 1));
  floatx4 x0 = *(const floatx4*)(X + base);
  floatx4 x1 = *(const floatx4*)(X + base + 4);
  floatx4 o0, o1;
  constexpr float invN = 1.f / (NB * NL);
  #pragma unroll
  for (int e = 0; e < 4; e++){
    int d = d0 + e;
    float mean = part[d] * invN;
    float var = part[1024 + d] * invN - mean * mean;
    float rstd = rsqrtf(var + 1e-5f);
    o0[e] = (x0[e] - mean) * rstd * G[d] + Bt[d];
    int d2 = d0 + 4 + e;
    float mean2 = part[d2] * invN;
    float var2 = part[1024 + d2] * invN - mean2 * mean2;
    float rstd2 = rsqrtf(var2 + 1e-5f);
    o1[e] = (x1[e] - mean2) * rstd2 * G[d2] + Bt[d2];
  }
  *(floatx4*)(X + base) = o0;
  *(floatx4*)(X + base + 4) = o1;
}

// ---------------------------------------------------------------------------
extern "C" void kernel_launch(void* const* d_in, const int* in_sizes, int n_in,
                              void* d_out, int out_size, void* d_ws, size_t ws_size,
                              hipStream_t stream){
  const float* q      = (const float*)d_in[0];
  const float* k      = (const float*)d_in[1];
  const float* v      = (const float*)d_in[2];
  const int*   mask   = (const int*)d_in[3];
  const float* w_qs   = (const float*)d_in[4];
  const float* w_ks   = (const float*)d_in[5];
  const float* w_vs   = (const float*)d_in[6];
  const float* proj_w = (const float*)d_in[7];
  const float* proj_b = (const float*)d_in[8];
  const float* gamma  = (const float*)d_in[9];
  const float* beta   = (const float*)d_in[10];

  float* out_x   = (float*)d_out;
  float* out_att = out_x + (size_t)NB * NL * ND;

  char* ws = (char*)d_ws;
  ushort* ctx = (ushort*)(ws);                       // 8 MB
  ushort* qh  = (ushort*)(ws + (24u << 20));
  ushort* kh  = (ushort*)(ws + (32u << 20));
  ushort* vt  = (ushort*)(ws + (40u << 20));         // transposed V
  ushort* wqT = (ushort*)(ws + (48u << 20));         // 2 MB each
  ushort* wkT = (ushort*)(ws + (50u << 20));
  ushort* wvT = (ushort*)(ws + (52u << 20));
  ushort* pwb = (ushort*)(ws + (54u << 20));
  unsigned long long* mb = (unsigned long long*)(ws + (56u << 20));  // 512 KB
  float*  part = (float*)(ws + (57u << 20));         // 8 KB

  dim3 blk(256);
  k_prep<<<dim3(768), blk, 0, stream>>>(w_qs, w_ks, w_vs, wqT, wkT, wvT);
  k_projm<<<dim3(8, 32, 4), blk, 0, stream>>>(q, k, v, wqT, wkT, wvT, qh, kh, vt,
                                              proj_w, pwb, mask, mb, part);
  k_attn<<<dim3(16, 64), blk, 0, stream>>>(qh, kh, vt, (const unsigned*)mb, out_att, ctx);
  k_projo<<<dim3(8, 32), blk, 0, stream>>>(ctx, pwb, proj_b, q, out_x, part);
  k_bnapply<<<dim3(NB * NL * ND / 8 / 256), blk, 0, stream>>>(out_x, part, gamma, beta);
}

// Round 17
// 184.409 us; speedup vs baseline: 1.0609x; 1.0609x over previous
//
#include <hip/hip_runtime.h>

typedef unsigned short ushort;
typedef __attribute__((ext_vector_type(4))) float floatx4;
typedef __bf16 bf16x8 __attribute__((ext_vector_type(8)));
typedef __bf16 bf16x4 __attribute__((ext_vector_type(4)));
typedef float f32x4 __attribute__((ext_vector_type(4)));

constexpr int NB = 4;     // batch
constexpr int NL = 1024;  // seq len
constexpr int ND = 1024;  // d_model
constexpr int NH = 16;    // heads
constexpr int NDK = 64;   // d_k = d_v

// Q is pre-scaled by log2(e)/32 so attn computes exp2(score) directly.
#define QSCALE 0.045084230079650879f

union B4 { bf16x4 v; unsigned long long ll; };

__device__ __forceinline__ void st_bf(ushort* dst, float f){
  union { __bf16 h; ushort u; } z; z.h = (__bf16)f; *dst = z.u;
}

#define MFMA(a,b,c) __builtin_amdgcn_mfma_f32_16x16x32_bf16((a),(b),(c),0,0,0)

// ---------------------------------------------------------------------------
// K0: merged prep (r15 structure).  Linear block ranges:
//   [0,512)      cast proj_w fp32 -> bf16
//   [512,1280)   transpose-cast w_qs/w_ks/w_vs -> WT(h,64,1024) bf16
//   [1280,5376)  mask int32 -> bit-pack (ballot)
//   5376         zero BN partial sums
// ---------------------------------------------------------------------------
__global__ __launch_bounds__(256) void k_prep(const float* __restrict__ pw,
                                              const float* __restrict__ w0,
                                              const float* __restrict__ w1,
                                              const float* __restrict__ w2,
                                              const int* __restrict__ M,
                                              ushort* __restrict__ pwb,
                                              ushort* __restrict__ t0,
                                              ushort* __restrict__ t1,
                                              ushort* __restrict__ t2,
                                              unsigned long long* __restrict__ MB,
                                              float* __restrict__ part){
  __shared__ ushort T[64][65];
  const int bid = blockIdx.x;
  const int tid = threadIdx.x;

  if (bid < 512){                       // ---- proj_w cast ----
    const size_t base = ((size_t)bid * 256 + tid) * 8;
    floatx4 v0 = *(const floatx4*)(pw + base);
    floatx4 v1 = *(const floatx4*)(pw + base + 4);
    bf16x8 o;
    #pragma unroll
    for (int j = 0; j < 4; j++){ o[j] = (__bf16)v0[j]; o[4 + j] = (__bf16)v1[j]; }
    *(bf16x8*)(pwb + base) = o;
    return;
  }
  if (bid < 1280){                      // ---- weight transpose ----
    const int r = bid - 512;
    const int z = r >> 8;
    const int h = (r >> 4) & 15, k0 = (r & 15) * 64;
    const float* src = (z == 0) ? w0 : (z == 1) ? w1 : w2;
    ushort* dst = (z == 0) ? t0 : (z == 1) ? t1 : t2;
    const int qd = tid >> 6, lo = tid & 63;
    #pragma unroll
    for (int i = 0; i < 16; i++){
      int kl = qd + i * 4;
      float f = src[((size_t)h * 1024 + k0 + kl) * 64 + lo];
      union { __bf16 h2; ushort u; } zz; zz.h2 = (__bf16)f;
      T[kl][lo] = zz.u;
    }
    __syncthreads();
    #pragma unroll
    for (int i = 0; i < 16; i++){
      int dk = qd + i * 4;
      dst[((size_t)h * 64 + dk) * 1024 + k0 + lo] = T[lo][dk];
    }
    return;
  }
  if (bid < 5376){                      // ---- mask pack ----
    const int r = bid - 1280;
    #pragma unroll
    for (int rep = 0; rep < 4; rep++){
      const int gid = r * 1024 + rep * 256 + tid;
      const int widx = gid >> 6;
      int m = M[(size_t)widx * 64 + (gid & 63)];
      unsigned long long bal = __ballot(m != 0);
      if ((gid & 63) == 0) MB[widx] = bal;
    }
    return;
  }
  // ---- zero BN partials ----
  *(floatx4*)(part + tid * 8) = f32x4{0.f, 0.f, 0.f, 0.f};
  *(floatx4*)(part + tid * 8 + 4) = f32x4{0.f, 0.f, 0.f, 0.f};
}

// ---------------------------------------------------------------------------
// K1: merged projections (z = 0:Q 1:K 2:V).  fp32 inputs, cast inline during
// A-staging.  z==0 epilogue pre-scaled by QSCALE; z==2 writes transposed
// VT(hb,64,1024).  XOR bank swizzle; XCD tile remap.
// ---------------------------------------------------------------------------
__global__ __launch_bounds__(256) void k_projm(const float* __restrict__ qf,
                                               const float* __restrict__ kf,
                                               const float* __restrict__ vf,
                                               const ushort* __restrict__ wqT,
                                               const ushort* __restrict__ wkT,
                                               const ushort* __restrict__ wvT,
                                               ushort* __restrict__ qh,
                                               ushort* __restrict__ kh,
                                               ushort* __restrict__ vt){
  __shared__ bf16x8 Ach[8 * 128];
  __shared__ bf16x8 Bch[8 * 128];
  const int z = blockIdx.z;
  const float* Xf = (z == 0) ? qf : (z == 1) ? kf : vf;
  const ushort* WT = (z == 0) ? wqT : (z == 1) ? wkT : wvT;
  const int tid = threadIdx.x;
  const int lane = tid & 63, wid = tid >> 6;
  const int g = lane >> 4, c = lane & 15;
  const int d = blockIdx.y * 8 + blockIdx.x;
  const int tile = (d & 7) * 32 + (d >> 3);
  const int row0 = (tile >> 3) * 128, col0 = (tile & 7) * 128;
  const int wm = (wid >> 1) * 64, wn = (wid & 1) * 64;

  f32x4 zero = {0.f, 0.f, 0.f, 0.f};
  f32x4 acc[4][4];
  #pragma unroll
  for (int i = 0; i < 4; i++)
    #pragma unroll
    for (int j = 0; j < 4; j++) acc[i][j] = zero;

  for (int k0 = 0; k0 < ND; k0 += 64){
    #pragma unroll
    for (int i = 0; i < 4; i++){
      int e = tid + i * 256;
      int kc = e & 7, m = e >> 3;
      const float* src = Xf + (size_t)(row0 + m) * ND + k0 + kc * 8;
      floatx4 v0 = *(const floatx4*)src;
      floatx4 v1 = *(const floatx4*)(src + 4);
      bf16x8 pb;
      #pragma unroll
      for (int j = 0; j < 4; j++){ pb[j] = (__bf16)v0[j]; pb[4 + j] = (__bf16)v1[j]; }
      Ach[kc * 128 + (m ^ kc)] = pb;
    }
    #pragma unroll
    for (int i = 0; i < 4; i++){
      int e = tid + i * 256;
      int kc = e & 7, n = e >> 3;
      int hh = (col0 + n) >> 6, dk = (col0 + n) & 63;
      Bch[kc * 128 + (n ^ kc)] = *(const bf16x8*)(WT + ((size_t)(hh << 6) + dk) * 1024 + k0 + kc * 8);
    }
    __syncthreads();
    bf16x8 bfr[4][2];
    #pragma unroll
    for (int ni = 0; ni < 4; ni++){
      int n = wn + ni * 16 + c;
      bfr[ni][0] = Bch[g * 128 + (n ^ g)];
      bfr[ni][1] = Bch[(4 + g) * 128 + (n ^ (4 + g))];
    }
    #pragma unroll
    for (int mi = 0; mi < 4; mi++){
      int m = wm + mi * 16 + c;
      bf16x8 a0 = Ach[g * 128 + (m ^ g)];
      bf16x8 a1 = Ach[(4 + g) * 128 + (m ^ (4 + g))];
      #pragma unroll
      for (int ni = 0; ni < 4; ni++){
        acc[mi][ni] = MFMA(a0, bfr[ni][0], acc[mi][ni]);
        acc[mi][ni] = MFMA(a1, bfr[ni][1], acc[mi][ni]);
      }
    }
    __syncthreads();
  }
  if (z == 2){
    #pragma unroll
    for (int mi = 0; mi < 4; mi++){
      #pragma unroll
      for (int ni = 0; ni < 4; ni++){
        int n = col0 + wn + ni * 16 + c;
        int hh = n >> 6, dk = n & 63;
        int m0 = row0 + wm + mi * 16 + g * 4;
        int bb = m0 >> 10, l = m0 & 1023;
        B4 o;
        #pragma unroll
        for (int r = 0; r < 4; r++) o.v[r] = (__bf16)acc[mi][ni][r];
        *(unsigned long long*)(vt + (((size_t)hh * NB + bb) * 64 + dk) * 1024 + l) = o.ll;
      }
    }
  } else {
    ushort* OUT = (z == 0) ? qh : kh;
    const float sc = (z == 0) ? QSCALE : 1.0f;
    #pragma unroll
    for (int mi = 0; mi < 4; mi++){
      #pragma unroll
      for (int ni = 0; ni < 4; ni++){
        #pragma unroll
        for (int r = 0; r < 4; r++){
          int m = row0 + wm + mi * 16 + g * 4 + r;
          int n = col0 + wn + ni * 16 + c;
          int bb = m >> 10, ls = m & 1023;
          int hh = n >> 6, dk = n & 63;
          st_bf(OUT + (((size_t)hh * NB + bb) * NL + ls) * NDK + dk, acc[mi][ni][r] * sc);
        }
      }
    }
  }
}

// ---------------------------------------------------------------------------
// K2: fused attention (r11/r15 structure) + T5 s_setprio around MFMA clusters
// (4 independent blocks/CU at different phases -> scheduler arbitration pays,
// per m191's attn regime; no semantic change).
// ---------------------------------------------------------------------------
__global__ __launch_bounds__(256, 4) void k_attn(const ushort* __restrict__ QH,
                                                 const ushort* __restrict__ KH,
                                                 const ushort* __restrict__ VT,
                                                 const unsigned* __restrict__ MB,
                                                 float* __restrict__ ATT,
                                                 ushort* __restrict__ CTX){
  __shared__ bf16x8 Kch[512];        // [sr][kc^(sr&7)]
  __shared__ bf16x8 Vch[512];        // [kc][dv^kc]
  __shared__ ushort Ps[4][16][72];
  __shared__ unsigned Ms[64 * 33];
  const int tid = threadIdx.x;
  const int lane = tid & 63, wid = tid >> 6;
  const int g = lane >> 4, c = lane & 15;
  const int d = blockIdx.y * 16 + blockIdx.x;
  const int tile = (d & 7) * 128 + (d >> 3);
  const int hb = tile >> 4;
  const int q0 = (tile & 15) * 64;
  const int h = hb >> 2, b = hb & 3;

  const int q = q0 + wid * 16 + c;
  const size_t qkbase = (size_t)hb * NL;

  bf16x8 qf0 = *(const bf16x8*)(QH + (qkbase + q) * NDK + g * 8);
  bf16x8 qf1 = *(const bf16x8*)(QH + (qkbase + q) * NDK + 32 + g * 8);

  {
    const unsigned* mbase = MB + ((size_t)(b << 10) + q0) * 32;
    #pragma unroll
    for (int i = 0; i < 8; i++){
      int idx = tid + i * 256;
      int ql2 = idx >> 5, word = idx & 31;
      Ms[ql2 * 33 + word] = mbase[ql2 * 32 + word];
    }
  }
  const int ql = wid * 16 + c;
  const int mg = g * 4;

  // staging indices (constant per thread)
  const int i0 = tid * 2, i1 = tid * 2 + 1;
  const int sr0 = i0 >> 3, kc0 = i0 & 7;
  const int sr1 = i1 >> 3, kc1 = i1 & 7;
  const int vdv0 = tid >> 3, vkc0 = tid & 7;            // idx = tid
  const int vdv1 = (tid + 256) >> 3, vkc1 = tid & 7;    // idx = tid + 256

  // ---- pass 1: denominators ----
  float rs = 0.f;
  bf16x8 kr0 = *(const bf16x8*)(KH + (qkbase + 0) * NDK + i0 * 8);
  bf16x8 kr1 = *(const bf16x8*)(KH + (qkbase + 0) * NDK + i1 * 8);
  for (int t = 0; t < 16; ++t){
    __syncthreads();
    Kch[sr0 * 8 + (kc0 ^ (sr0 & 7))] = kr0;
    Kch[sr1 * 8 + (kc1 ^ (sr1 & 7))] = kr1;
    __syncthreads();
    if (t < 15){
      const ushort* knext = KH + (qkbase + (t + 1) * 64) * NDK;
      kr0 = *(const bf16x8*)(knext + i0 * 8);
      kr1 = *(const bf16x8*)(knext + i1 * 8);
    }
    __builtin_amdgcn_s_setprio(1);
    #pragma unroll
    for (int sub2 = 0; sub2 < 4; ++sub2){
      int s = sub2 * 16 + c;
      bf16x8 kf0 = Kch[s * 8 + (g ^ (s & 7))];
      bf16x8 kf1 = Kch[s * 8 + ((4 + g) ^ (s & 7))];
      f32x4 a = {0.f, 0.f, 0.f, 0.f};
      a = MFMA(kf0, qf0, a);
      a = MFMA(kf1, qf1, a);
      unsigned w = Ms[ql * 33 + t * 2 + (sub2 >> 1)];
      unsigned bits4 = (w >> (((sub2 & 1) << 4) + mg)) & 0xFu;
      #pragma unroll
      for (int r = 0; r < 4; r++)
        rs += ((bits4 >> r) & 1u) ? 0.f : __builtin_amdgcn_exp2f(a[r]);
    }
    __builtin_amdgcn_s_setprio(0);
  }
  rs += __shfl_xor(rs, 16);
  rs += __shfl_xor(rs, 32);
  const float lsh = -__log2f(rs);

  // ---- pass 2: attns write + PV ----
  f32x4 acc[4];
  #pragma unroll
  for (int i = 0; i < 4; i++) acc[i] = f32x4{0.f, 0.f, 0.f, 0.f};
  const f32x4 cin = {lsh, lsh, lsh, lsh};

  kr0 = *(const bf16x8*)(KH + (qkbase + 0) * NDK + i0 * 8);
  kr1 = *(const bf16x8*)(KH + (qkbase + 0) * NDK + i1 * 8);
  bf16x8 vr0 = *(const bf16x8*)(VT + ((size_t)hb * 64 + vdv0) * 1024 + vkc0 * 8);
  bf16x8 vr1 = *(const bf16x8*)(VT + ((size_t)hb * 64 + vdv1) * 1024 + vkc1 * 8);

  for (int t = 0; t < 16; ++t){
    __syncthreads();
    Kch[sr0 * 8 + (kc0 ^ (sr0 & 7))] = kr0;
    Kch[sr1 * 8 + (kc1 ^ (sr1 & 7))] = kr1;
    Vch[vkc0 * 64 + (vdv0 ^ vkc0)] = vr0;
    Vch[vkc1 * 64 + (vdv1 ^ vkc1)] = vr1;
    __syncthreads();
    if (t < 15){
      const ushort* knext = KH + (qkbase + (t + 1) * 64) * NDK;
      kr0 = *(const bf16x8*)(knext + i0 * 8);
      kr1 = *(const bf16x8*)(knext + i1 * 8);
      const ushort* vnext = VT + (size_t)hb * 64 * 1024 + (t + 1) * 64;
      vr0 = *(const bf16x8*)(vnext + (size_t)vdv0 * 1024 + vkc0 * 8);
      vr1 = *(const bf16x8*)(vnext + (size_t)vdv1 * 1024 + vkc1 * 8);
    }
    __builtin_amdgcn_s_setprio(1);
    #pragma unroll
    for (int sub2 = 0; sub2 < 4; ++sub2){
      int s = sub2 * 16 + c;
      bf16x8 kf0 = Kch[s * 8 + (g ^ (s & 7))];
      bf16x8 kf1 = Kch[s * 8 + ((4 + g) ^ (s & 7))];
      f32x4 a = cin;
      a = MFMA(kf0, qf0, a);
      a = MFMA(kf1, qf1, a);
      unsigned w = Ms[ql * 33 + t * 2 + (sub2 >> 1)];
      unsigned bits4 = (w >> (((sub2 & 1) << 4) + mg)) & 0xFu;
      floatx4 pn;
      B4 pw;
      #pragma unroll
      for (int r = 0; r < 4; r++){
        float p = ((bits4 >> r) & 1u) ? 0.f : __builtin_amdgcn_exp2f(a[r]);
        pn[r] = p;
        pw.v[r] = (__bf16)p;
      }
      *(floatx4*)(ATT + ((size_t)hb * NL + q) * NL + (t * 4 + sub2) * 16 + g * 4) = pn;
      *(unsigned long long*)&Ps[wid][c][sub2 * 16 + g * 4] = pw.ll;
    }
    #pragma unroll
    for (int ss = 0; ss < 2; ++ss){
      bf16x8 afr = *(bf16x8*)&Ps[wid][c][ss * 32 + g * 8];
      #pragma unroll
      for (int ni = 0; ni < 4; ni++){
        int kcr = ss * 4 + g;
        bf16x8 vfr = Vch[kcr * 64 + ((ni * 16 + c) ^ kcr)];
        acc[ni] = MFMA(afr, vfr, acc[ni]);
      }
    }
    __builtin_amdgcn_s_setprio(0);
  }

  #pragma unroll
  for (int ni = 0; ni < 4; ni++)
    #pragma unroll
    for (int r = 0; r < 4; r++){
      int qq = q0 + wid * 16 + g * 4 + r;
      int dv = ni * 16 + c;
      st_bf(CTX + ((size_t)b * NL + qq) * ND + h * NDK + dv, acc[ni][r]);
    }
}

// ---------------------------------------------------------------------------
// K4: output projection + bias + residual + fused BN partial sums (atomics)
// ---------------------------------------------------------------------------
__global__ __launch_bounds__(256) void k_projo(const ushort* __restrict__ CTX,
                                               const ushort* __restrict__ PWb,
                                               const float* __restrict__ PB,
                                               const float* __restrict__ RES,
                                               float* __restrict__ X,
                                               float* __restrict__ part){
  __shared__ bf16x8 Ach[8 * 128];
  __shared__ bf16x8 Bch[8 * 128];
  const int tid = threadIdx.x;
  const int lane = tid & 63, wid = tid >> 6;
  const int g = lane >> 4, c = lane & 15;
  const int d = blockIdx.y * 8 + blockIdx.x;
  const int tile = (d & 7) * 32 + (d >> 3);
  const int row0 = (tile >> 3) * 128, col0 = (tile & 7) * 128;
  const int wm = (wid >> 1) * 64, wn = (wid & 1) * 64;

  f32x4 zero = {0.f, 0.f, 0.f, 0.f};
  f32x4 acc[4][4];
  #pragma unroll
  for (int i = 0; i < 4; i++)
    #pragma unroll
    for (int j = 0; j < 4; j++) acc[i][j] = zero;

  for (int k0 = 0; k0 < ND; k0 += 64){
    #pragma unroll
    for (int i = 0; i < 4; i++){
      int e = tid + i * 256;
      int kc = e & 7, m = e >> 3;
      Ach[kc * 128 + (m ^ kc)] = *(const bf16x8*)(CTX + (size_t)(row0 + m) * ND + k0 + kc * 8);
    }
    #pragma unroll
    for (int i = 0; i < 4; i++){
      int e = tid + i * 256;
      int kc = e & 7, n = e >> 3;
      Bch[kc * 128 + (n ^ kc)] = *(const bf16x8*)(PWb + (size_t)(col0 + n) * 1024 + k0 + kc * 8);
    }
    __syncthreads();
    bf16x8 bfr[4][2];
    #pragma unroll
    for (int ni = 0; ni < 4; ni++){
      int n = wn + ni * 16 + c;
      bfr[ni][0] = Bch[g * 128 + (n ^ g)];
      bfr[ni][1] = Bch[(4 + g) * 128 + (n ^ (4 + g))];
    }
    #pragma unroll
    for (int mi = 0; mi < 4; mi++){
      int m = wm + mi * 16 + c;
      bf16x8 a0 = Ach[g * 128 + (m ^ g)];
      bf16x8 a1 = Ach[(4 + g) * 128 + (m ^ (4 + g))];
      #pragma unroll
      for (int ni = 0; ni < 4; ni++){
        acc[mi][ni] = MFMA(a0, bfr[ni][0], acc[mi][ni]);
        acc[mi][ni] = MFMA(a1, bfr[ni][1], acc[mi][ni]);
      }
    }
    __syncthreads();
  }
  float s_[4] = {0.f, 0.f, 0.f, 0.f}, s2_[4] = {0.f, 0.f, 0.f, 0.f};
  #pragma unroll
  for (int mi = 0; mi < 4; mi++)
    #pragma unroll
    for (int ni = 0; ni < 4; ni++)
      #pragma unroll
      for (int r = 0; r < 4; r++){
        int m = row0 + wm + mi * 16 + g * 4 + r;
        int n = col0 + wn + ni * 16 + c;
        float val = acc[mi][ni][r] + PB[n] + RES[(size_t)m * ND + n];
        X[(size_t)m * ND + n] = val;
        s_[ni] += val; s2_[ni] += val * val;
      }
  #pragma unroll
  for (int ni = 0; ni < 4; ni++){
    float a = s_[ni], b2 = s2_[ni];
    a += __shfl_xor(a, 16); b2 += __shfl_xor(b2, 16);
    a += __shfl_xor(a, 32); b2 += __shfl_xor(b2, 32);
    if (g == 0){
      int n = col0 + wn + ni * 16 + c;
      atomicAdd(&part[n], a);
      atomicAdd(&part[1024 + n], b2);
    }
  }
}

// ---------------------------------------------------------------------------
// K5: BN finalize + apply in place
// ---------------------------------------------------------------------------
__global__ __launch_bounds__(256) void k_bnapply(float* __restrict__ X,
                                                 const float* __restrict__ part,
                                                 const float* __restrict__ G,
                                                 const float* __restrict__ Bt){
  const int idx = blockIdx.x * 256 + threadIdx.x;
  const size_t base = (size_t)idx * 8;
  const int d0 = (int)(base & (ND - 1));
  floatx4 x0 = *(const floatx4*)(X + base);
  floatx4 x1 = *(const floatx4*)(X + base + 4);
  floatx4 o0, o1;
  constexpr float invN = 1.f / (NB * NL);
  #pragma unroll
  for (int e = 0; e < 4; e++){
    int d = d0 + e;
    float mean = part[d] * invN;
    float var = part[1024 + d] * invN - mean * mean;
    float rstd = rsqrtf(var + 1e-5f);
    o0[e] = (x0[e] - mean) * rstd * G[d] + Bt[d];
    int d2 = d0 + 4 + e;
    float mean2 = part[d2] * invN;
    float var2 = part[1024 + d2] * invN - mean2 * mean2;
    float rstd2 = rsqrtf(var2 + 1e-5f);
    o1[e] = (x1[e] - mean2) * rstd2 * G[d2] + Bt[d2];
  }
  *(floatx4*)(X + base) = o0;
  *(floatx4*)(X + base + 4) = o1;
}

// ---------------------------------------------------------------------------
extern "C" void kernel_launch(void* const* d_in, const int* in_sizes, int n_in,
                              void* d_out, int out_size, void* d_ws, size_t ws_size,
                              hipStream_t stream){
  const float* q      = (const float*)d_in[0];
  const float* k      = (const float*)d_in[1];
  const float* v      = (const float*)d_in[2];
  const int*   mask   = (const int*)d_in[3];
  const float* w_qs   = (const float*)d_in[4];
  const float* w_ks   = (const float*)d_in[5];
  const float* w_vs   = (const float*)d_in[6];
  const float* proj_w = (const float*)d_in[7];
  const float* proj_b = (const float*)d_in[8];
  const float* gamma  = (const float*)d_in[9];
  const float* beta   = (const float*)d_in[10];

  float* out_x   = (float*)d_out;
  float* out_att = out_x + (size_t)NB * NL * ND;

  char* ws = (char*)d_ws;
  ushort* ctx = (ushort*)(ws);                       // 8 MB
  ushort* qh  = (ushort*)(ws + (24u << 20));
  ushort* kh  = (ushort*)(ws + (32u << 20));
  ushort* vt  = (ushort*)(ws + (40u << 20));         // transposed V
  ushort* wqT = (ushort*)(ws + (48u << 20));         // 2 MB each
  ushort* wkT = (ushort*)(ws + (50u << 20));
  ushort* wvT = (ushort*)(ws + (52u << 20));
  ushort* pwb = (ushort*)(ws + (54u << 20));
  unsigned long long* mb = (unsigned long long*)(ws + (56u << 20));  // 512 KB
  float*  part = (float*)(ws + (57u << 20));         // 8 KB

  dim3 blk(256);
  k_prep<<<dim3(5377), blk, 0, stream>>>(proj_w, w_qs, w_ks, w_vs, mask,
                                         pwb, wqT, wkT, wvT, mb, part);
  k_projm<<<dim3(8, 32, 3), blk, 0, stream>>>(q, k, v, wqT, wkT, wvT, qh, kh, vt);
  k_attn<<<dim3(16, 64), blk, 0, stream>>>(qh, kh, vt, (const unsigned*)mb, out_att, ctx);
  k_projo<<<dim3(8, 32), blk, 0, stream>>>(ctx, pwb, proj_b, q, out_x, part);
  k_bnapply<<<dim3(NB * NL * ND / 8 / 256), blk, 0, stream>>>(out_x, part, gamma, beta);
}